// Round 1
// baseline (2540.168 us; speedup 1.0000x reference)
//
#include <hip/hip_runtime.h>

// TopDownTreeLSTM on MI355X — round 6: data-is-the-flag dataflow.
// Replaces per-level done[] counters with sentinel-poisoned H/C: producers
// just store (relaxed, agent scope) and move on; consumers poll the parent
// data itself (NaN sentinels) — the successful poll IS the data load.
// Cuts the per-hop LLC round trips from ~4 (store-ack + flag-add + poll +
// data-load) to ~2 (sentry detect + full poll) and removes all level-wide
// straggler waits. A 1-lane sentry with s_sleep throttles idle-block poll
// traffic to ~1 load / 700 cyc / block.

#define NN 32768
#define DD 256
#define GP 1024
#define SENT_C 0x7FC00001u   // f32 NaN payload: real c is always finite
#define SENT_H 0xFFFFFFFFu   // bf16 -NaN pair: real h = sig*tanh in (-1,1)

typedef __attribute__((ext_vector_type(8))) short short8;
typedef __attribute__((ext_vector_type(4))) float float4_;
typedef __attribute__((ext_vector_type(4))) unsigned uint4_;

static __device__ __forceinline__ unsigned short f2bf(float f) {
    unsigned u = __builtin_bit_cast(unsigned, f);
    unsigned r = u + 0x7FFFu + ((u >> 16) & 1u);
    return (unsigned short)(r >> 16);
}
static __device__ __forceinline__ float bf2f(unsigned short u) {
    unsigned v = ((unsigned)u) << 16;
    return __builtin_bit_cast(float, v);
}
static __device__ __forceinline__ float sigf(float x) { return 1.0f / (1.0f + __expf(-x)); }
static __device__ __forceinline__ float tanh_(float x) { return 1.0f - 2.0f / (__expf(2.0f * x) + 1.0f); }

// Poison C (f32 NaN) and Hb (bf16 -NaN pairs); zero scheduling scratch.
// Grid must be exactly 2048 x 256 (524288 threads).
__global__ void k_init(int* cnt, int* cur, int* maxd, float* C, unsigned* HbU) {
    const int g = blockIdx.x * 256 + threadIdx.x;
    if (g < NN + 2) { cnt[g] = 0; cur[g] = 0; }
    if (g == 0) maxd[0] = 0;
    const uint4_ sc = (uint4_){SENT_C, SENT_C, SENT_C, SENT_C};
    const uint4_ sh = (uint4_){SENT_H, SENT_H, SENT_H, SENT_H};
    uint4_* Cu = (uint4_*)C;          // NN*DD/4   = 2097152 uint4
    uint4_* Hu = (uint4_*)HbU;        // NN*DD/8   = 1048576 uint4
    #pragma unroll
    for (int k = 0; k < 4; ++k) Cu[(size_t)g + (size_t)k * 524288] = sc;
    #pragma unroll
    for (int k = 0; k < 2; ++k) Hu[(size_t)g + (size_t)k * 524288] = sh;
}

__global__ void k_root(const float* __restrict__ X, const float* __restrict__ state,
                       const float* __restrict__ rootW, const float* __restrict__ rootb,
                       const int* __restrict__ idx,
                       unsigned short* __restrict__ Hb, float* __restrict__ C) {
    const int t = threadIdx.x;
    const int row = idx[0];
    const float4_* xr = (const float4_*)(X + (size_t)row * DD);
    const float4_* wr = (const float4_*)(rootW + (size_t)t * DD);
    float acc = rootb[t];
    for (int k = 0; k < DD / 4; ++k) {
        float4_ a = xr[k], b = wr[k];
        acc += a[0] * b[0] + a[1] * b[1] + a[2] * b[2] + a[3] * b[3];
    }
    Hb[t] = f2bf(tanh_(acc));
    C[t] = state[t];
    // kernel-end release makes these visible to k_tree2's agent-scope loads
}

__global__ void k_dep_init(const int* __restrict__ parents, int* dep, int* jmp) {
    int i = blockIdx.x * 256 + threadIdx.x;
    if (i >= NN) return;
    dep[i] = (i == 0) ? 0 : 1;
    jmp[i] = (i == 0) ? 0 : parents[i];
}

__global__ void k_dep_step(const int* __restrict__ depA, const int* __restrict__ jmpA,
                           int* __restrict__ depB, int* __restrict__ jmpB) {
    int i = blockIdx.x * 256 + threadIdx.x;
    if (i >= NN) return;
    int j = jmpA[i];
    depB[i] = depA[i] + depA[j];
    jmpB[i] = jmpA[j];
}

__global__ void k_hist(const int* __restrict__ dep, int* cnt, int* maxd) {
    int i = blockIdx.x * 256 + threadIdx.x;
    if (i >= NN) return;
    int d = dep[i];
    atomicAdd(&cnt[d], 1);
    atomicMax(&maxd[0], d);
}

__global__ void k_scan(const int* __restrict__ cnt, int* __restrict__ off) {
    __shared__ int sums[256];
    const int tid = threadIdx.x;
    const int base = tid * 128;
    int s = 0;
    for (int k = 0; k < 128; ++k) s += cnt[base + k];
    sums[tid] = s;
    __syncthreads();
    if (tid == 0) {
        int run = 0;
        for (int t = 0; t < 256; ++t) { int tmp = sums[t]; sums[t] = run; run += tmp; }
    }
    __syncthreads();
    int run = sums[tid];
    for (int k = 0; k < 128; ++k) { off[base + k] = run; run += cnt[base + k]; }
    if (tid == 255) off[NN] = run;
}

__global__ void k_scatter(const int* __restrict__ dep, const int* __restrict__ off,
                          int* cur, int* __restrict__ lev) {
    int i = blockIdx.x * 256 + threadIdx.x;
    if (i >= NN) return;
    int d = dep[i];
    int pos = off[d] + atomicAdd(&cur[d], 1);
    lev[pos] = i;
}

// Throughput GEMM: Gpre[n][g] = sum_k X[idx[n]][k]*Wih[g][k] + bih[g] + bhh[g], bf16 out.
__global__ __launch_bounds__(256, 1) void k_gx(
    const float* __restrict__ X, const float* __restrict__ Wih,
    const float* __restrict__ bih, const float* __restrict__ bhh,
    const int* __restrict__ idx, unsigned short* __restrict__ Gp) {
    __shared__ __align__(16) short bw_s[128 * 264];
    __shared__ float bias_s[128];
    const int tid = threadIdx.x;
    const int w = tid >> 6, l = tid & 63;
    const int lanelo = l & 15, quad = l >> 4;

    short8 a[2][8];
    #pragma unroll
    for (int ti = 0; ti < 2; ++ti) {
        int n = (blockIdx.x * 8 + w * 2 + ti) * 16 + lanelo;
        int row = idx[n];
        const float* xp = X + (size_t)row * DD + quad * 8;
        #pragma unroll
        for (int ks = 0; ks < 8; ++ks) {
            float4_ x0 = *(const float4_*)(xp + ks * 32);
            float4_ x1 = *(const float4_*)(xp + ks * 32 + 4);
            short8 s;
            s[0] = f2bf(x0[0]); s[1] = f2bf(x0[1]); s[2] = f2bf(x0[2]); s[3] = f2bf(x0[3]);
            s[4] = f2bf(x1[0]); s[5] = f2bf(x1[1]); s[6] = f2bf(x1[2]); s[7] = f2bf(x1[3]);
            a[ti][ks] = s;
        }
    }
    for (int gc = 0; gc < 8; ++gc) {
        __syncthreads();
        for (int e = tid; e < 128 * 64; e += 256) {
            int r = e >> 6, c4 = (e & 63) * 4;
            float4_ b = *(const float4_*)(Wih + (size_t)(gc * 128 + r) * DD + c4);
            unsigned short* pb = (unsigned short*)&bw_s[r * 264 + c4];
            pb[0] = f2bf(b[0]); pb[1] = f2bf(b[1]); pb[2] = f2bf(b[2]); pb[3] = f2bf(b[3]);
        }
        if (tid < 128) bias_s[tid] = bih[gc * 128 + tid] + bhh[gc * 128 + tid];
        __syncthreads();
        #pragma unroll
        for (int ntl = 0; ntl < 8; ++ntl) {
            float4_ acc0 = (float4_){0.f, 0.f, 0.f, 0.f};
            float4_ acc1 = (float4_){0.f, 0.f, 0.f, 0.f};
            #pragma unroll
            for (int ks = 0; ks < 8; ++ks) {
                short8 bf = *(const short8*)&bw_s[(ntl * 16 + lanelo) * 264 + ks * 32 + quad * 8];
                acc0 = __builtin_amdgcn_mfma_f32_16x16x32_bf16(a[0][ks], bf, acc0, 0, 0, 0);
                acc1 = __builtin_amdgcn_mfma_f32_16x16x32_bf16(a[1][ks], bf, acc1, 0, 0, 0);
            }
            float bia = bias_s[ntl * 16 + lanelo];
            int g = gc * 128 + ntl * 16 + lanelo;
            int nb0 = (blockIdx.x * 8 + w * 2) * 16 + quad * 4;
            #pragma unroll
            for (int r = 0; r < 4; ++r) {
                Gp[(size_t)(nb0 + r) * GP + g] = f2bf(acc0[r] + bia);
                Gp[(size_t)(nb0 + 16 + r) * GP + g] = f2bf(acc1[r] + bia);
            }
        }
    }
}

__global__ __launch_bounds__(256, 1) void k_tree2(
    const float* __restrict__ Whh,
    const int* __restrict__ parents,
    const int* __restrict__ off, const int* __restrict__ lev, const int* __restrict__ maxd_g,
    const unsigned short* __restrict__ Gp,
    unsigned short* __restrict__ Hb, float* __restrict__ C) {

    __shared__ __align__(16) short w_s[128 * 264];   // W_hh slice, bf16, K=256
    __shared__ __align__(16) short A_s[16 * 264];    // parent H rows, bf16
    __shared__ __align__(16) float G_s[16 * 128];    // Gpre tile (this block's 128 gate cols)
    __shared__ __align__(16) float R_s[16 * 132];    // recurrent gate partials
    __shared__ int nd_s[16], par_s[16];

    const int tid = threadIdx.x;
    const int j = blockIdx.x & 7, grp = blockIdx.x >> 3;
    const int w = tid >> 6, l = tid & 63;
    const int lanelo = l & 15, quad = l >> 4;

    // Stage W_hh slice: local row r -> global gate-row (r>>5)*256 + j*32 + (r&31)
    for (int e = tid; e < 128 * 64; e += 256) {
        int r = e >> 6, c4 = (e & 63) * 4;
        int G = ((r >> 5) * 256) + j * 32 + (r & 31);
        float4_ b = *(const float4_*)(Whh + (size_t)G * DD + c4);
        unsigned short* pb = (unsigned short*)&w_s[r * 264 + c4];
        pb[0] = f2bf(b[0]); pb[1] = f2bf(b[1]); pb[2] = f2bf(b[2]); pb[3] = f2bf(b[3]);
    }
    __syncthreads();

    const unsigned* HbU = (const unsigned*)Hb;
    const int maxd = maxd_g[0];
    int lo = off[1];
    for (int d = 1; d <= maxd; ++d) {
        const int hi = off[d + 1];
        const int tiles = (hi - lo + 15) >> 4;
        for (int t = grp; t < tiles; t += 32) {
            const int base = lo + t * 16;
            if (tid < 16) {
                int node = -1, p = 0;
                if (base + tid < hi) { node = lev[base + tid]; p = parents[node]; }
                nd_s[tid] = node; par_s[tid] = p;
            }
            __syncthreads();
            // Prefetch Gpre tile (no parent dependency).
            {
                int m = tid >> 4, q8 = (tid & 15) * 8;
                int seg = q8 >> 5, cc = q8 & 31;
                float4_ g01 = (float4_){0.f, 0.f, 0.f, 0.f};
                float4_ g23 = (float4_){0.f, 0.f, 0.f, 0.f};
                if (nd_s[m] >= 0) {
                    const unsigned short* gp =
                        Gp + (size_t)nd_s[m] * GP + seg * 256 + j * 32 + cc;
                    short8 gv = *(const short8*)gp;
                    g01[0] = bf2f(gv[0]); g01[1] = bf2f(gv[1]); g01[2] = bf2f(gv[2]); g01[3] = bf2f(gv[3]);
                    g23[0] = bf2f(gv[4]); g23[1] = bf2f(gv[5]); g23[2] = bf2f(gv[6]); g23[3] = bf2f(gv[7]);
                }
                *(float4_*)&G_s[m * 128 + q8] = g01;
                *(float4_*)&G_s[m * 128 + q8 + 4] = g23;
            }
            // Sentry: one lane watches one H word of slot-0's parent (this
            // slice's own columns), throttled by s_sleep. Keeps idle-block
            // poll traffic to ~1 load / 700 cyc / block.
            if (tid == 0) {
                const unsigned* sp = &HbU[(size_t)par_s[0] * 128 + j * 16];
                while (__hip_atomic_load(sp, __ATOMIC_RELAXED, __HIP_MEMORY_SCOPE_AGENT) == SENT_H)
                    __builtin_amdgcn_s_sleep(1);
            }
            __syncthreads();
            // Full poll: the data IS the flag. Successful poll returns the
            // parent C values and H words directly — no separate acquire+load.
            const int m0 = tid >> 5, c0 = tid & 31, col = j * 32 + c0;
            float cp0 = 0.f, cp1 = 0.f;
            unsigned hv[8];
            bool ok = false;
            while (true) {
                if (!ok) {
                    bool good = true;
                    cp0 = __hip_atomic_load(&C[(size_t)par_s[m0] * DD + col],
                                            __ATOMIC_RELAXED, __HIP_MEMORY_SCOPE_AGENT);
                    cp1 = __hip_atomic_load(&C[(size_t)par_s[m0 + 8] * DD + col],
                                            __ATOMIC_RELAXED, __HIP_MEMORY_SCOPE_AGENT);
                    if (nd_s[m0] >= 0 && __builtin_bit_cast(unsigned, cp0) == SENT_C) good = false;
                    if (nd_s[m0 + 8] >= 0 && __builtin_bit_cast(unsigned, cp1) == SENT_C) good = false;
                    #pragma unroll
                    for (int k2 = 0; k2 < 8; ++k2) {
                        const int e = tid + k2 * 256, m = e >> 7, cu = e & 127;
                        if (nd_s[m] >= 0) {
                            hv[k2] = __hip_atomic_load(&HbU[(size_t)par_s[m] * 128 + cu],
                                                       __ATOMIC_RELAXED, __HIP_MEMORY_SCOPE_AGENT);
                            if (hv[k2] == SENT_H) good = false;
                        } else {
                            hv[k2] = 0u;
                        }
                    }
                    ok = good;
                }
                if (__syncthreads_and(ok ? 1 : 0)) break;
                __builtin_amdgcn_s_sleep(1);
            }
            // Stage parent H into LDS.
            #pragma unroll
            for (int k2 = 0; k2 < 8; ++k2) {
                const int e = tid + k2 * 256, m = e >> 7, cu = e & 127;
                *(unsigned*)&A_s[m * 264 + cu * 2] = hv[k2];
            }
            __syncthreads();
            // M=16 K=256 MFMA -> R_s
            {
                short8 af[8];
                #pragma unroll
                for (int ks = 0; ks < 8; ++ks)
                    af[ks] = *(const short8*)&A_s[lanelo * 264 + ks * 32 + quad * 8];
                #pragma unroll
                for (int ti = 0; ti < 2; ++ti) {
                    int ntl = w * 2 + ti;
                    float4_ acc = (float4_){0.f, 0.f, 0.f, 0.f};
                    #pragma unroll
                    for (int ks = 0; ks < 8; ++ks) {
                        short8 bf = *(const short8*)&w_s[(ntl * 16 + lanelo) * 264 + ks * 32 + quad * 8];
                        acc = __builtin_amdgcn_mfma_f32_16x16x32_bf16(af[ks], bf, acc, 0, 0, 0);
                    }
                    #pragma unroll
                    for (int r = 0; r < 4; ++r)
                        R_s[(quad * 4 + r) * 132 + ntl * 16 + lanelo] = acc[r];
                }
            }
            __syncthreads();
            // Elementwise LSTM for the block's 32 cols; plain relaxed stores,
            // no fence, no flag — the stored values are the readiness signal.
            {
                #pragma unroll
                for (int pass = 0; pass < 2; ++pass) {
                    int m = m0 + pass * 8;
                    float cp = pass ? cp1 : cp0;
                    float ig = R_s[m * 132 + c0]      + G_s[m * 128 + c0];
                    float fg = R_s[m * 132 + 32 + c0] + G_s[m * 128 + 32 + c0];
                    float gg = R_s[m * 132 + 64 + c0] + G_s[m * 128 + 64 + c0];
                    float og = R_s[m * 132 + 96 + c0] + G_s[m * 128 + 96 + c0];
                    float cn = sigf(fg) * cp + sigf(ig) * tanh_(gg);
                    float hn = sigf(og) * tanh_(cn);
                    int node = nd_s[m];
                    unsigned short hs = f2bf(hn);
                    unsigned pair = ((unsigned)hs) |
                                    (((unsigned)(unsigned short)__shfl_down((int)hs, 1)) << 16);
                    if (node >= 0) {
                        __hip_atomic_store(&C[(size_t)node * DD + col], cn,
                                           __ATOMIC_RELAXED, __HIP_MEMORY_SCOPE_AGENT);
                        if ((c0 & 1) == 0)
                            __hip_atomic_store(&((unsigned*)Hb)[(size_t)node * 128 + (col >> 1)],
                                               pair, __ATOMIC_RELAXED, __HIP_MEMORY_SCOPE_AGENT);
                    }
                }
            }
            __syncthreads();
        }
        lo = hi;
    }
}

__global__ void k_out(const unsigned short* __restrict__ Hb, const float* __restrict__ C,
                      const int* __restrict__ idx, float* __restrict__ out) {
    const int b = blockIdx.x, t = threadIdx.x;
    if (b < NN) {
        int drow = idx[b];
        out[512 + (size_t)drow * DD + t] = bf2f(Hb[(size_t)b * DD + t]);
    } else {
        out[t] = C[t];
        out[DD + t] = bf2f(Hb[t]);
    }
}

extern "C" void kernel_launch(void* const* d_in, const int* in_sizes, int n_in,
                              void* d_out, int out_size, void* d_ws, size_t ws_size,
                              hipStream_t stream) {
    const float* X     = (const float*)d_in[0];
    const float* state = (const float*)d_in[1];
    const float* rootW = (const float*)d_in[2];
    const float* rootb = (const float*)d_in[3];
    const float* Wih   = (const float*)d_in[4];
    const float* Whh   = (const float*)d_in[5];
    const float* bih   = (const float*)d_in[6];
    const float* bhh   = (const float*)d_in[7];
    const int* parents = (const int*)d_in[8];
    const int* idx     = (const int*)d_in[9];

    float* C           = (float*)d_ws;                                   // 32 MiB
    unsigned short* Hb = (unsigned short*)(C + (size_t)NN * DD);         // 16 MiB
    unsigned short* Gp = Hb + (size_t)NN * DD;                           // 64 MiB
    int* ip            = (int*)(Gp + (size_t)NN * GP);
    int* depA = ip;            ip += NN;
    int* jmpA = ip;            ip += NN;
    int* depB = ip;            ip += NN;
    int* jmpB = ip;            ip += NN;
    int* cnt  = ip;            ip += NN + 2;
    int* off  = ip;            ip += NN + 2;
    int* cur  = ip;            ip += NN + 2;
    int* lev  = ip;            ip += NN;
    int* maxd = ip;            ip += 4;
    float* out = (float*)d_out;

    k_init<<<dim3(2048), dim3(256), 0, stream>>>(cnt, cur, maxd, C, (unsigned*)Hb);
    k_root<<<dim3(1), dim3(256), 0, stream>>>(X, state, rootW, rootb, idx, Hb, C);

    k_dep_init<<<dim3(128), dim3(256), 0, stream>>>(parents, depA, jmpA);
    int* dA = depA; int* jA = jmpA; int* dB = depB; int* jB = jmpB;
    for (int it = 0; it < 15; ++it) {
        k_dep_step<<<dim3(128), dim3(256), 0, stream>>>(dA, jA, dB, jB);
        int* tp;
        tp = dA; dA = dB; dB = tp;
        tp = jA; jA = jB; jB = tp;
    }
    k_hist<<<dim3(128), dim3(256), 0, stream>>>(dA, cnt, maxd);
    k_scan<<<dim3(1), dim3(256), 0, stream>>>(cnt, off);
    k_scatter<<<dim3(128), dim3(256), 0, stream>>>(dA, off, cur, lev);

    k_gx<<<dim3(256), dim3(256), 0, stream>>>(X, Wih, bih, bhh, idx, Gp);
    k_tree2<<<dim3(256), dim3(256), 0, stream>>>(Whh, parents, off, lev, maxd, Gp, Hb, C);
    k_out<<<dim3(NN + 1), dim3(256), 0, stream>>>(Hb, C, idx, out);
}

// Round 2
// 1856.207 us; speedup vs baseline: 1.3685x; 1.3685x over previous
//
#include <hip/hip_runtime.h>

// TopDownTreeLSTM on MI355X — round 7: sentinel dataflow + producer fence.
// r6 post-mortem: removing the producer release fence made store visibility
// lazy (drain deferred behind subsequent work), and the barrier-per-iteration
// full poll was expensive -> +51%. r7 keeps r6's flag-free per-parent waits
// (kills flag-publish RT + flag->data serialization + level-straggler waits)
// but restores r5's per-tile wg-release fence (s_waitcnt only, prompt drain),
// and makes waiting cheap: a 16-lane tight-spin sentry (1 word per parent
// slot) + per-thread per-word validated retries (no barriers in retry path).

#define NN 32768
#define DD 256
#define GP 1024
#define SENT_C 0x7FC00001u   // f32 NaN payload: real c is always finite
#define SENT_H 0xFFFFFFFFu   // bf16 -NaN pair: real h = sig*tanh in (-1,1)

typedef __attribute__((ext_vector_type(8))) short short8;
typedef __attribute__((ext_vector_type(4))) float float4_;
typedef __attribute__((ext_vector_type(4))) unsigned uint4_;

static __device__ __forceinline__ unsigned short f2bf(float f) {
    unsigned u = __builtin_bit_cast(unsigned, f);
    unsigned r = u + 0x7FFFu + ((u >> 16) & 1u);
    return (unsigned short)(r >> 16);
}
static __device__ __forceinline__ float bf2f(unsigned short u) {
    unsigned v = ((unsigned)u) << 16;
    return __builtin_bit_cast(float, v);
}
static __device__ __forceinline__ float sigf(float x) { return 1.0f / (1.0f + __expf(-x)); }
static __device__ __forceinline__ float tanh_(float x) { return 1.0f - 2.0f / (__expf(2.0f * x) + 1.0f); }

// Poison C (f32 NaN) and Hb (bf16 -NaN pairs); zero scheduling scratch.
// Grid must be exactly 2048 x 256 (524288 threads).
__global__ void k_init(int* cnt, int* cur, int* maxd, float* C, unsigned* HbU) {
    const int g = blockIdx.x * 256 + threadIdx.x;
    if (g < NN + 2) { cnt[g] = 0; cur[g] = 0; }
    if (g == 0) maxd[0] = 0;
    const uint4_ sc = (uint4_){SENT_C, SENT_C, SENT_C, SENT_C};
    const uint4_ sh = (uint4_){SENT_H, SENT_H, SENT_H, SENT_H};
    uint4_* Cu = (uint4_*)C;          // NN*DD/4   = 2097152 uint4
    uint4_* Hu = (uint4_*)HbU;        // NN*DD/8   = 1048576 uint4
    #pragma unroll
    for (int k = 0; k < 4; ++k) Cu[(size_t)g + (size_t)k * 524288] = sc;
    #pragma unroll
    for (int k = 0; k < 2; ++k) Hu[(size_t)g + (size_t)k * 524288] = sh;
}

__global__ void k_root(const float* __restrict__ X, const float* __restrict__ state,
                       const float* __restrict__ rootW, const float* __restrict__ rootb,
                       const int* __restrict__ idx,
                       unsigned short* __restrict__ Hb, float* __restrict__ C) {
    const int t = threadIdx.x;
    const int row = idx[0];
    const float4_* xr = (const float4_*)(X + (size_t)row * DD);
    const float4_* wr = (const float4_*)(rootW + (size_t)t * DD);
    float acc = rootb[t];
    for (int k = 0; k < DD / 4; ++k) {
        float4_ a = xr[k], b = wr[k];
        acc += a[0] * b[0] + a[1] * b[1] + a[2] * b[2] + a[3] * b[3];
    }
    Hb[t] = f2bf(tanh_(acc));
    C[t] = state[t];
    // kernel-end release makes these visible to k_tree2's agent-scope loads
}

__global__ void k_dep_init(const int* __restrict__ parents, int* dep, int* jmp) {
    int i = blockIdx.x * 256 + threadIdx.x;
    if (i >= NN) return;
    dep[i] = (i == 0) ? 0 : 1;
    jmp[i] = (i == 0) ? 0 : parents[i];
}

__global__ void k_dep_step(const int* __restrict__ depA, const int* __restrict__ jmpA,
                           int* __restrict__ depB, int* __restrict__ jmpB) {
    int i = blockIdx.x * 256 + threadIdx.x;
    if (i >= NN) return;
    int j = jmpA[i];
    depB[i] = depA[i] + depA[j];
    jmpB[i] = jmpA[j];
}

__global__ void k_hist(const int* __restrict__ dep, int* cnt, int* maxd) {
    int i = blockIdx.x * 256 + threadIdx.x;
    if (i >= NN) return;
    int d = dep[i];
    atomicAdd(&cnt[d], 1);
    atomicMax(&maxd[0], d);
}

__global__ void k_scan(const int* __restrict__ cnt, int* __restrict__ off) {
    __shared__ int sums[256];
    const int tid = threadIdx.x;
    const int base = tid * 128;
    int s = 0;
    for (int k = 0; k < 128; ++k) s += cnt[base + k];
    sums[tid] = s;
    __syncthreads();
    if (tid == 0) {
        int run = 0;
        for (int t = 0; t < 256; ++t) { int tmp = sums[t]; sums[t] = run; run += tmp; }
    }
    __syncthreads();
    int run = sums[tid];
    for (int k = 0; k < 128; ++k) { off[base + k] = run; run += cnt[base + k]; }
    if (tid == 255) off[NN] = run;
}

__global__ void k_scatter(const int* __restrict__ dep, const int* __restrict__ off,
                          int* cur, int* __restrict__ lev) {
    int i = blockIdx.x * 256 + threadIdx.x;
    if (i >= NN) return;
    int d = dep[i];
    int pos = off[d] + atomicAdd(&cur[d], 1);
    lev[pos] = i;
}

// Throughput GEMM: Gpre[n][g] = sum_k X[idx[n]][k]*Wih[g][k] + bih[g] + bhh[g], bf16 out.
__global__ __launch_bounds__(256, 1) void k_gx(
    const float* __restrict__ X, const float* __restrict__ Wih,
    const float* __restrict__ bih, const float* __restrict__ bhh,
    const int* __restrict__ idx, unsigned short* __restrict__ Gp) {
    __shared__ __align__(16) short bw_s[128 * 264];
    __shared__ float bias_s[128];
    const int tid = threadIdx.x;
    const int w = tid >> 6, l = tid & 63;
    const int lanelo = l & 15, quad = l >> 4;

    short8 a[2][8];
    #pragma unroll
    for (int ti = 0; ti < 2; ++ti) {
        int n = (blockIdx.x * 8 + w * 2 + ti) * 16 + lanelo;
        int row = idx[n];
        const float* xp = X + (size_t)row * DD + quad * 8;
        #pragma unroll
        for (int ks = 0; ks < 8; ++ks) {
            float4_ x0 = *(const float4_*)(xp + ks * 32);
            float4_ x1 = *(const float4_*)(xp + ks * 32 + 4);
            short8 s;
            s[0] = f2bf(x0[0]); s[1] = f2bf(x0[1]); s[2] = f2bf(x0[2]); s[3] = f2bf(x0[3]);
            s[4] = f2bf(x1[0]); s[5] = f2bf(x1[1]); s[6] = f2bf(x1[2]); s[7] = f2bf(x1[3]);
            a[ti][ks] = s;
        }
    }
    for (int gc = 0; gc < 8; ++gc) {
        __syncthreads();
        for (int e = tid; e < 128 * 64; e += 256) {
            int r = e >> 6, c4 = (e & 63) * 4;
            float4_ b = *(const float4_*)(Wih + (size_t)(gc * 128 + r) * DD + c4);
            unsigned short* pb = (unsigned short*)&bw_s[r * 264 + c4];
            pb[0] = f2bf(b[0]); pb[1] = f2bf(b[1]); pb[2] = f2bf(b[2]); pb[3] = f2bf(b[3]);
        }
        if (tid < 128) bias_s[tid] = bih[gc * 128 + tid] + bhh[gc * 128 + tid];
        __syncthreads();
        #pragma unroll
        for (int ntl = 0; ntl < 8; ++ntl) {
            float4_ acc0 = (float4_){0.f, 0.f, 0.f, 0.f};
            float4_ acc1 = (float4_){0.f, 0.f, 0.f, 0.f};
            #pragma unroll
            for (int ks = 0; ks < 8; ++ks) {
                short8 bf = *(const short8*)&bw_s[(ntl * 16 + lanelo) * 264 + ks * 32 + quad * 8];
                acc0 = __builtin_amdgcn_mfma_f32_16x16x32_bf16(a[0][ks], bf, acc0, 0, 0, 0);
                acc1 = __builtin_amdgcn_mfma_f32_16x16x32_bf16(a[1][ks], bf, acc1, 0, 0, 0);
            }
            float bia = bias_s[ntl * 16 + lanelo];
            int g = gc * 128 + ntl * 16 + lanelo;
            int nb0 = (blockIdx.x * 8 + w * 2) * 16 + quad * 4;
            #pragma unroll
            for (int r = 0; r < 4; ++r) {
                Gp[(size_t)(nb0 + r) * GP + g] = f2bf(acc0[r] + bia);
                Gp[(size_t)(nb0 + 16 + r) * GP + g] = f2bf(acc1[r] + bia);
            }
        }
    }
}

__global__ __launch_bounds__(256, 1) void k_tree2(
    const float* __restrict__ Whh,
    const int* __restrict__ parents,
    const int* __restrict__ off, const int* __restrict__ lev, const int* __restrict__ maxd_g,
    const unsigned short* __restrict__ Gp,
    unsigned short* __restrict__ Hb, float* __restrict__ C) {

    __shared__ __align__(16) short w_s[128 * 264];   // W_hh slice, bf16, K=256
    __shared__ __align__(16) short A_s[16 * 264];    // parent H rows, bf16
    __shared__ __align__(16) float G_s[16 * 128];    // Gpre tile (this block's 128 gate cols)
    __shared__ __align__(16) float R_s[16 * 132];    // recurrent gate partials
    __shared__ int nd_s[16], par_s[16];

    const int tid = threadIdx.x;
    const int j = blockIdx.x & 7, grp = blockIdx.x >> 3;
    const int w = tid >> 6, l = tid & 63;
    const int lanelo = l & 15, quad = l >> 4;

    // Stage W_hh slice: local row r -> global gate-row (r>>5)*256 + j*32 + (r&31)
    for (int e = tid; e < 128 * 64; e += 256) {
        int r = e >> 6, c4 = (e & 63) * 4;
        int G = ((r >> 5) * 256) + j * 32 + (r & 31);
        float4_ b = *(const float4_*)(Whh + (size_t)G * DD + c4);
        unsigned short* pb = (unsigned short*)&w_s[r * 264 + c4];
        pb[0] = f2bf(b[0]); pb[1] = f2bf(b[1]); pb[2] = f2bf(b[2]); pb[3] = f2bf(b[3]);
    }
    __syncthreads();

    const unsigned* HbU = (const unsigned*)Hb;
    const int maxd = maxd_g[0];
    int lo = off[1];
    for (int d = 1; d <= maxd; ++d) {
        const int hi = off[d + 1];
        const int tiles = (hi - lo + 15) >> 4;
        for (int t = grp; t < tiles; t += 32) {
            const int base = lo + t * 16;
            if (tid < 16) {
                int node = -1, p = 0;
                if (base + tid < hi) { node = lev[base + tid]; p = parents[node]; }
                nd_s[tid] = node; par_s[tid] = p;
            }
            __syncthreads();
            // Prefetch Gpre tile (no parent dependency).
            {
                int m = tid >> 4, q8 = (tid & 15) * 8;
                int seg = q8 >> 5, cc = q8 & 31;
                float4_ g01 = (float4_){0.f, 0.f, 0.f, 0.f};
                float4_ g23 = (float4_){0.f, 0.f, 0.f, 0.f};
                if (nd_s[m] >= 0) {
                    const unsigned short* gp =
                        Gp + (size_t)nd_s[m] * GP + seg * 256 + j * 32 + cc;
                    short8 gv = *(const short8*)gp;
                    g01[0] = bf2f(gv[0]); g01[1] = bf2f(gv[1]); g01[2] = bf2f(gv[2]); g01[3] = bf2f(gv[3]);
                    g23[0] = bf2f(gv[4]); g23[1] = bf2f(gv[5]); g23[2] = bf2f(gv[6]); g23[3] = bf2f(gv[7]);
                }
                *(float4_*)&G_s[m * 128 + q8] = g01;
                *(float4_*)&G_s[m * 128 + q8 + 4] = g23;
            }
            // Multi-sentry: wave 0, lanes 0-15 tight-spin on the first H word
            // (this block's own j-slice) of each parent slot. 16x4B loads per
            // RT per block -> negligible LLC traffic even spinning untrottled.
            if (tid < 64) {
                const int m = tid & 15;
                const bool act = (tid < 16) && (nd_s[m] >= 0);
                const unsigned* sp = &HbU[(size_t)par_s[m] * 128 + j * 16];
                bool miss = act && (__hip_atomic_load(sp, __ATOMIC_RELAXED,
                                                      __HIP_MEMORY_SCOPE_AGENT) == SENT_H);
                while (__any(miss ? 1 : 0))
                    miss = act && (__hip_atomic_load(sp, __ATOMIC_RELAXED,
                                                     __HIP_MEMORY_SCOPE_AGENT) == SENT_H);
            }
            __syncthreads();
            // Validated parent loads: issue all 10 pipelined, then retry only
            // still-sentinel words (producer fence makes the window tiny).
            const int m0 = tid >> 5, c0 = tid & 31, col = j * 32 + c0;
            float* cpp0 = &C[(size_t)par_s[m0] * DD + col];
            float* cpp1 = &C[(size_t)par_s[m0 + 8] * DD + col];
            float cp0 = __hip_atomic_load(cpp0, __ATOMIC_RELAXED, __HIP_MEMORY_SCOPE_AGENT);
            float cp1 = __hip_atomic_load(cpp1, __ATOMIC_RELAXED, __HIP_MEMORY_SCOPE_AGENT);
            unsigned hv[8];
            #pragma unroll
            for (int k2 = 0; k2 < 8; ++k2) {
                const int e = tid + k2 * 256, m = e >> 7, cu = e & 127;
                hv[k2] = (nd_s[m] >= 0)
                    ? __hip_atomic_load(&HbU[(size_t)par_s[m] * 128 + cu],
                                        __ATOMIC_RELAXED, __HIP_MEMORY_SCOPE_AGENT)
                    : 0u;
            }
            if (nd_s[m0] >= 0)
                while (__builtin_bit_cast(unsigned, cp0) == SENT_C) {
                    __builtin_amdgcn_s_sleep(1);
                    cp0 = __hip_atomic_load(cpp0, __ATOMIC_RELAXED, __HIP_MEMORY_SCOPE_AGENT);
                }
            if (nd_s[m0 + 8] >= 0)
                while (__builtin_bit_cast(unsigned, cp1) == SENT_C) {
                    __builtin_amdgcn_s_sleep(1);
                    cp1 = __hip_atomic_load(cpp1, __ATOMIC_RELAXED, __HIP_MEMORY_SCOPE_AGENT);
                }
            #pragma unroll
            for (int k2 = 0; k2 < 8; ++k2) {
                const int e = tid + k2 * 256, m = e >> 7, cu = e & 127;
                if (nd_s[m] >= 0)
                    while (hv[k2] == SENT_H) {
                        __builtin_amdgcn_s_sleep(1);
                        hv[k2] = __hip_atomic_load(&HbU[(size_t)par_s[m] * 128 + cu],
                                                   __ATOMIC_RELAXED, __HIP_MEMORY_SCOPE_AGENT);
                    }
            }
            // Stage parent H into LDS.
            #pragma unroll
            for (int k2 = 0; k2 < 8; ++k2) {
                const int e = tid + k2 * 256, m = e >> 7, cu = e & 127;
                *(unsigned*)&A_s[m * 264 + cu * 2] = hv[k2];
            }
            __syncthreads();
            // M=16 K=256 MFMA -> R_s
            {
                short8 af[8];
                #pragma unroll
                for (int ks = 0; ks < 8; ++ks)
                    af[ks] = *(const short8*)&A_s[lanelo * 264 + ks * 32 + quad * 8];
                #pragma unroll
                for (int ti = 0; ti < 2; ++ti) {
                    int ntl = w * 2 + ti;
                    float4_ acc = (float4_){0.f, 0.f, 0.f, 0.f};
                    #pragma unroll
                    for (int ks = 0; ks < 8; ++ks) {
                        short8 bf = *(const short8*)&w_s[(ntl * 16 + lanelo) * 264 + ks * 32 + quad * 8];
                        acc = __builtin_amdgcn_mfma_f32_16x16x32_bf16(af[ks], bf, acc, 0, 0, 0);
                    }
                    #pragma unroll
                    for (int r = 0; r < 4; ++r)
                        R_s[(quad * 4 + r) * 132 + ntl * 16 + lanelo] = acc[r];
                }
            }
            __syncthreads();
            // Elementwise LSTM for the block's 32 cols; relaxed stores, then
            // a per-tile wg-release fence (s_waitcnt only) forces prompt drain
            // so consumers' sentinel polls see the data ASAP.
            {
                #pragma unroll
                for (int pass = 0; pass < 2; ++pass) {
                    int m = m0 + pass * 8;
                    float cp = pass ? cp1 : cp0;
                    float ig = R_s[m * 132 + c0]      + G_s[m * 128 + c0];
                    float fg = R_s[m * 132 + 32 + c0] + G_s[m * 128 + 32 + c0];
                    float gg = R_s[m * 132 + 64 + c0] + G_s[m * 128 + 64 + c0];
                    float og = R_s[m * 132 + 96 + c0] + G_s[m * 128 + 96 + c0];
                    float cn = sigf(fg) * cp + sigf(ig) * tanh_(gg);
                    float hn = sigf(og) * tanh_(cn);
                    int node = nd_s[m];
                    unsigned short hs = f2bf(hn);
                    unsigned pair = ((unsigned)hs) |
                                    (((unsigned)(unsigned short)__shfl_down((int)hs, 1)) << 16);
                    if (node >= 0) {
                        __hip_atomic_store(&C[(size_t)node * DD + col], cn,
                                           __ATOMIC_RELAXED, __HIP_MEMORY_SCOPE_AGENT);
                        if ((c0 & 1) == 0)
                            __hip_atomic_store(&((unsigned*)Hb)[(size_t)node * 128 + (col >> 1)],
                                               pair, __ATOMIC_RELAXED, __HIP_MEMORY_SCOPE_AGENT);
                    }
                }
            }
            __builtin_amdgcn_fence(__ATOMIC_RELEASE, "workgroup");
            __syncthreads();
        }
        lo = hi;
    }
}

__global__ void k_out(const unsigned short* __restrict__ Hb, const float* __restrict__ C,
                      const int* __restrict__ idx, float* __restrict__ out) {
    const int b = blockIdx.x, t = threadIdx.x;
    if (b < NN) {
        int drow = idx[b];
        out[512 + (size_t)drow * DD + t] = bf2f(Hb[(size_t)b * DD + t]);
    } else {
        out[t] = C[t];
        out[DD + t] = bf2f(Hb[t]);
    }
}

extern "C" void kernel_launch(void* const* d_in, const int* in_sizes, int n_in,
                              void* d_out, int out_size, void* d_ws, size_t ws_size,
                              hipStream_t stream) {
    const float* X     = (const float*)d_in[0];
    const float* state = (const float*)d_in[1];
    const float* rootW = (const float*)d_in[2];
    const float* rootb = (const float*)d_in[3];
    const float* Wih   = (const float*)d_in[4];
    const float* Whh   = (const float*)d_in[5];
    const float* bih   = (const float*)d_in[6];
    const float* bhh   = (const float*)d_in[7];
    const int* parents = (const int*)d_in[8];
    const int* idx     = (const int*)d_in[9];

    float* C           = (float*)d_ws;                                   // 32 MiB
    unsigned short* Hb = (unsigned short*)(C + (size_t)NN * DD);         // 16 MiB
    unsigned short* Gp = Hb + (size_t)NN * DD;                           // 64 MiB
    int* ip            = (int*)(Gp + (size_t)NN * GP);
    int* depA = ip;            ip += NN;
    int* jmpA = ip;            ip += NN;
    int* depB = ip;            ip += NN;
    int* jmpB = ip;            ip += NN;
    int* cnt  = ip;            ip += NN + 2;
    int* off  = ip;            ip += NN + 2;
    int* cur  = ip;            ip += NN + 2;
    int* lev  = ip;            ip += NN;
    int* maxd = ip;            ip += 4;
    float* out = (float*)d_out;

    k_init<<<dim3(2048), dim3(256), 0, stream>>>(cnt, cur, maxd, C, (unsigned*)Hb);
    k_root<<<dim3(1), dim3(256), 0, stream>>>(X, state, rootW, rootb, idx, Hb, C);

    k_dep_init<<<dim3(128), dim3(256), 0, stream>>>(parents, depA, jmpA);
    int* dA = depA; int* jA = jmpA; int* dB = depB; int* jB = jmpB;
    for (int it = 0; it < 15; ++it) {
        k_dep_step<<<dim3(128), dim3(256), 0, stream>>>(dA, jA, dB, jB);
        int* tp;
        tp = dA; dA = dB; dB = tp;
        tp = jA; jA = jB; jB = tp;
    }
    k_hist<<<dim3(128), dim3(256), 0, stream>>>(dA, cnt, maxd);
    k_scan<<<dim3(1), dim3(256), 0, stream>>>(cnt, off);
    k_scatter<<<dim3(128), dim3(256), 0, stream>>>(dA, off, cur, lev);

    k_gx<<<dim3(256), dim3(256), 0, stream>>>(X, Wih, bih, bhh, idx, Gp);
    k_tree2<<<dim3(256), dim3(256), 0, stream>>>(Whh, parents, off, lev, maxd, Gp, Hb, C);
    k_out<<<dim3(NN + 1), dim3(256), 0, stream>>>(Hb, C, idx, out);
}

// Round 3
// 1763.506 us; speedup vs baseline: 1.4404x; 1.0526x over previous
//
#include <hip/hip_runtime.h>

// TopDownTreeLSTM on MI355X — round 8: hop-latency surgery.
// r7 ~= r5 (sentinel ~= flag) => per-hop path is what both share. r8 removes
// three serial hop components: (1) off[] cached in LDS (no per-level global
// load chain; idle blocks skip levels at LDS rate); (2) volley-first poll:
// in chain lockstep the first all-words volley usually succeeds (own slice
// fenced-visible, siblings in lockstep) -> collapses sentry-RT + load-RT into
// one volley; miss path = r7 sentry + per-word revalidate (idle blocks cheap);
// (3) next-tile (lev,parents) register prefetch issued under the poll shadow.
// Producer fence retained (r6 proved lazy drain is catastrophic).

#define NN 32768
#define DD 256
#define GP 1024
#define OFFCAP 4096
#define SENT_C 0x7FC00001u   // f32 NaN payload: real c is always finite
#define SENT_H 0xFFFFFFFFu   // bf16 -NaN pair: real h = sig*tanh in (-1,1)

typedef __attribute__((ext_vector_type(8))) short short8;
typedef __attribute__((ext_vector_type(4))) float float4_;
typedef __attribute__((ext_vector_type(4))) unsigned uint4_;

static __device__ __forceinline__ unsigned short f2bf(float f) {
    unsigned u = __builtin_bit_cast(unsigned, f);
    unsigned r = u + 0x7FFFu + ((u >> 16) & 1u);
    return (unsigned short)(r >> 16);
}
static __device__ __forceinline__ float bf2f(unsigned short u) {
    unsigned v = ((unsigned)u) << 16;
    return __builtin_bit_cast(float, v);
}
static __device__ __forceinline__ float sigf(float x) { return 1.0f / (1.0f + __expf(-x)); }
static __device__ __forceinline__ float tanh_(float x) { return 1.0f - 2.0f / (__expf(2.0f * x) + 1.0f); }

// Poison C (f32 NaN) and Hb (bf16 -NaN pairs); zero scheduling scratch.
// Grid must be exactly 2048 x 256 (524288 threads).
__global__ void k_init(int* cnt, int* cur, int* maxd, float* C, unsigned* HbU) {
    const int g = blockIdx.x * 256 + threadIdx.x;
    if (g < NN + 2) { cnt[g] = 0; cur[g] = 0; }
    if (g == 0) maxd[0] = 0;
    const uint4_ sc = (uint4_){SENT_C, SENT_C, SENT_C, SENT_C};
    const uint4_ sh = (uint4_){SENT_H, SENT_H, SENT_H, SENT_H};
    uint4_* Cu = (uint4_*)C;          // NN*DD/4   = 2097152 uint4
    uint4_* Hu = (uint4_*)HbU;        // NN*DD/8   = 1048576 uint4
    #pragma unroll
    for (int k = 0; k < 4; ++k) Cu[(size_t)g + (size_t)k * 524288] = sc;
    #pragma unroll
    for (int k = 0; k < 2; ++k) Hu[(size_t)g + (size_t)k * 524288] = sh;
}

__global__ void k_root(const float* __restrict__ X, const float* __restrict__ state,
                       const float* __restrict__ rootW, const float* __restrict__ rootb,
                       const int* __restrict__ idx,
                       unsigned short* __restrict__ Hb, float* __restrict__ C) {
    const int t = threadIdx.x;
    const int row = idx[0];
    const float4_* xr = (const float4_*)(X + (size_t)row * DD);
    const float4_* wr = (const float4_*)(rootW + (size_t)t * DD);
    float acc = rootb[t];
    for (int k = 0; k < DD / 4; ++k) {
        float4_ a = xr[k], b = wr[k];
        acc += a[0] * b[0] + a[1] * b[1] + a[2] * b[2] + a[3] * b[3];
    }
    Hb[t] = f2bf(tanh_(acc));
    C[t] = state[t];
}

__global__ void k_dep_init(const int* __restrict__ parents, int* dep, int* jmp) {
    int i = blockIdx.x * 256 + threadIdx.x;
    if (i >= NN) return;
    dep[i] = (i == 0) ? 0 : 1;
    jmp[i] = (i == 0) ? 0 : parents[i];
}

__global__ void k_dep_step(const int* __restrict__ depA, const int* __restrict__ jmpA,
                           int* __restrict__ depB, int* __restrict__ jmpB) {
    int i = blockIdx.x * 256 + threadIdx.x;
    if (i >= NN) return;
    int j = jmpA[i];
    depB[i] = depA[i] + depA[j];
    jmpB[i] = jmpA[j];
}

__global__ void k_hist(const int* __restrict__ dep, int* cnt, int* maxd) {
    int i = blockIdx.x * 256 + threadIdx.x;
    if (i >= NN) return;
    int d = dep[i];
    atomicAdd(&cnt[d], 1);
    atomicMax(&maxd[0], d);
}

__global__ void k_scan(const int* __restrict__ cnt, int* __restrict__ off) {
    __shared__ int sums[256];
    const int tid = threadIdx.x;
    const int base = tid * 128;
    int s = 0;
    for (int k = 0; k < 128; ++k) s += cnt[base + k];
    sums[tid] = s;
    __syncthreads();
    if (tid == 0) {
        int run = 0;
        for (int t = 0; t < 256; ++t) { int tmp = sums[t]; sums[t] = run; run += tmp; }
    }
    __syncthreads();
    int run = sums[tid];
    for (int k = 0; k < 128; ++k) { off[base + k] = run; run += cnt[base + k]; }
    if (tid == 255) off[NN] = run;
}

__global__ void k_scatter(const int* __restrict__ dep, const int* __restrict__ off,
                          int* cur, int* __restrict__ lev) {
    int i = blockIdx.x * 256 + threadIdx.x;
    if (i >= NN) return;
    int d = dep[i];
    int pos = off[d] + atomicAdd(&cur[d], 1);
    lev[pos] = i;
}

// Throughput GEMM: Gpre[n][g] = sum_k X[idx[n]][k]*Wih[g][k] + bih[g] + bhh[g], bf16 out.
__global__ __launch_bounds__(256, 1) void k_gx(
    const float* __restrict__ X, const float* __restrict__ Wih,
    const float* __restrict__ bih, const float* __restrict__ bhh,
    const int* __restrict__ idx, unsigned short* __restrict__ Gp) {
    __shared__ __align__(16) short bw_s[128 * 264];
    __shared__ float bias_s[128];
    const int tid = threadIdx.x;
    const int w = tid >> 6, l = tid & 63;
    const int lanelo = l & 15, quad = l >> 4;

    short8 a[2][8];
    #pragma unroll
    for (int ti = 0; ti < 2; ++ti) {
        int n = (blockIdx.x * 8 + w * 2 + ti) * 16 + lanelo;
        int row = idx[n];
        const float* xp = X + (size_t)row * DD + quad * 8;
        #pragma unroll
        for (int ks = 0; ks < 8; ++ks) {
            float4_ x0 = *(const float4_*)(xp + ks * 32);
            float4_ x1 = *(const float4_*)(xp + ks * 32 + 4);
            short8 s;
            s[0] = f2bf(x0[0]); s[1] = f2bf(x0[1]); s[2] = f2bf(x0[2]); s[3] = f2bf(x0[3]);
            s[4] = f2bf(x1[0]); s[5] = f2bf(x1[1]); s[6] = f2bf(x1[2]); s[7] = f2bf(x1[3]);
            a[ti][ks] = s;
        }
    }
    for (int gc = 0; gc < 8; ++gc) {
        __syncthreads();
        for (int e = tid; e < 128 * 64; e += 256) {
            int r = e >> 6, c4 = (e & 63) * 4;
            float4_ b = *(const float4_*)(Wih + (size_t)(gc * 128 + r) * DD + c4);
            unsigned short* pb = (unsigned short*)&bw_s[r * 264 + c4];
            pb[0] = f2bf(b[0]); pb[1] = f2bf(b[1]); pb[2] = f2bf(b[2]); pb[3] = f2bf(b[3]);
        }
        if (tid < 128) bias_s[tid] = bih[gc * 128 + tid] + bhh[gc * 128 + tid];
        __syncthreads();
        #pragma unroll
        for (int ntl = 0; ntl < 8; ++ntl) {
            float4_ acc0 = (float4_){0.f, 0.f, 0.f, 0.f};
            float4_ acc1 = (float4_){0.f, 0.f, 0.f, 0.f};
            #pragma unroll
            for (int ks = 0; ks < 8; ++ks) {
                short8 bf = *(const short8*)&bw_s[(ntl * 16 + lanelo) * 264 + ks * 32 + quad * 8];
                acc0 = __builtin_amdgcn_mfma_f32_16x16x32_bf16(a[0][ks], bf, acc0, 0, 0, 0);
                acc1 = __builtin_amdgcn_mfma_f32_16x16x32_bf16(a[1][ks], bf, acc1, 0, 0, 0);
            }
            float bia = bias_s[ntl * 16 + lanelo];
            int g = gc * 128 + ntl * 16 + lanelo;
            int nb0 = (blockIdx.x * 8 + w * 2) * 16 + quad * 4;
            #pragma unroll
            for (int r = 0; r < 4; ++r) {
                Gp[(size_t)(nb0 + r) * GP + g] = f2bf(acc0[r] + bia);
                Gp[(size_t)(nb0 + 16 + r) * GP + g] = f2bf(acc1[r] + bia);
            }
        }
    }
}

__global__ __launch_bounds__(256, 1) void k_tree2(
    const float* __restrict__ Whh,
    const int* __restrict__ parents,
    const int* __restrict__ off, const int* __restrict__ lev, const int* __restrict__ maxd_g,
    const unsigned short* __restrict__ Gp,
    unsigned short* __restrict__ Hb, float* __restrict__ C) {

    __shared__ __align__(16) short w_s[128 * 264];   // W_hh slice, bf16, K=256
    __shared__ __align__(16) short A_s[16 * 264];    // parent H rows, bf16
    __shared__ __align__(16) float G_s[16 * 128];    // Gpre tile (this block's 128 gate cols)
    __shared__ __align__(16) float R_s[16 * 132];    // recurrent gate partials
    __shared__ int off_s[OFFCAP];                    // level offsets (LDS-rate)
    __shared__ int nd_s[16], par_s[16];

    const int tid = threadIdx.x;
    const int j = blockIdx.x & 7, grp = blockIdx.x >> 3;
    const int w = tid >> 6, l = tid & 63;
    const int lanelo = l & 15, quad = l >> 4;

    // Stage W_hh slice: local row r -> global gate-row (r>>5)*256 + j*32 + (r&31)
    for (int e = tid; e < 128 * 64; e += 256) {
        int r = e >> 6, c4 = (e & 63) * 4;
        int G = ((r >> 5) * 256) + j * 32 + (r & 31);
        float4_ b = *(const float4_*)(Whh + (size_t)G * DD + c4);
        unsigned short* pb = (unsigned short*)&w_s[r * 264 + c4];
        pb[0] = f2bf(b[0]); pb[1] = f2bf(b[1]); pb[2] = f2bf(b[2]); pb[3] = f2bf(b[3]);
    }
    const int maxd = maxd_g[0];
    const int staged = (maxd + 2 < OFFCAP) ? (maxd + 2) : OFFCAP;
    for (int e = tid; e < staged; e += 256) off_s[e] = off[e];
    __syncthreads();

    #define OFFS(i) (((i) < staged) ? off_s[(i)] : off[(i)])

    const unsigned* HbU = (const unsigned*)Hb;
    // Next-tile (node,parent) register prefetch; meaningful in lanes tid<16.
    int pn_node = -1, pn_par = 0;
    bool pn_valid = false;

    int lo = OFFS(1);
    for (int d = 1; d <= maxd; ++d) {
        const int hi = OFFS(d + 1);
        const int tiles = (hi - lo + 15) >> 4;
        for (int t = grp; t < tiles; t += 32) {
            const int base = lo + t * 16;
            if (tid < 16) {
                if (pn_valid) {
                    nd_s[tid] = pn_node; par_s[tid] = pn_par;
                } else {
                    int node = -1, p = 0;
                    if (base + tid < hi) { node = lev[base + tid]; p = parents[node]; }
                    nd_s[tid] = node; par_s[tid] = p;
                }
            }
            pn_valid = false;
            __syncthreads();
            // Prefetch Gpre tile (no parent dependency) — overlaps the poll.
            {
                int m = tid >> 4, q8 = (tid & 15) * 8;
                int seg = q8 >> 5, cc = q8 & 31;
                float4_ g01 = (float4_){0.f, 0.f, 0.f, 0.f};
                float4_ g23 = (float4_){0.f, 0.f, 0.f, 0.f};
                if (nd_s[m] >= 0) {
                    const unsigned short* gp =
                        Gp + (size_t)nd_s[m] * GP + seg * 256 + j * 32 + cc;
                    short8 gv = *(const short8*)gp;
                    g01[0] = bf2f(gv[0]); g01[1] = bf2f(gv[1]); g01[2] = bf2f(gv[2]); g01[3] = bf2f(gv[3]);
                    g23[0] = bf2f(gv[4]); g23[1] = bf2f(gv[5]); g23[2] = bf2f(gv[6]); g23[3] = bf2f(gv[7]);
                }
                *(float4_*)&G_s[m * 128 + q8] = g01;
                *(float4_*)&G_s[m * 128 + q8 + 4] = g23;
            }
            // Next-tile (lev,parents) prefetch — static data, safe anytime;
            // issued here so the dependent load chain hides under the poll.
            {
                int nt_base = -1, nt_hi = hi;
                if (t + 32 < tiles) {
                    nt_base = lo + (t + 32) * 16;
                } else if (d < maxd) {
                    const int hi2 = OFFS(d + 2);
                    const int tiles2 = (hi2 - hi + 15) >> 4;
                    if (grp < tiles2) { nt_base = hi + grp * 16; nt_hi = hi2; }
                }
                if (nt_base >= 0) {
                    if (tid < 16) {
                        int node = -1, p = 0;
                        if (nt_base + tid < nt_hi) { node = lev[nt_base + tid]; p = parents[node]; }
                        pn_node = node; pn_par = p;
                    }
                    pn_valid = true;
                }
            }
            // Volley-first poll: all threads load all their words once and
            // validate. In chain lockstep this usually succeeds on try 1
            // (own slice fenced-visible, sibling blocks in lockstep).
            const int m0 = tid >> 5, c0 = tid & 31, col = j * 32 + c0;
            float* cpp0 = &C[(size_t)par_s[m0] * DD + col];
            float* cpp1 = &C[(size_t)par_s[m0 + 8] * DD + col];
            float cp0 = __hip_atomic_load(cpp0, __ATOMIC_RELAXED, __HIP_MEMORY_SCOPE_AGENT);
            float cp1 = __hip_atomic_load(cpp1, __ATOMIC_RELAXED, __HIP_MEMORY_SCOPE_AGENT);
            unsigned hv[8];
            bool ok = true;
            #pragma unroll
            for (int k2 = 0; k2 < 8; ++k2) {
                const int e = tid + k2 * 256, m = e >> 7, cu = e & 127;
                hv[k2] = (nd_s[m] >= 0)
                    ? __hip_atomic_load(&HbU[(size_t)par_s[m] * 128 + cu],
                                        __ATOMIC_RELAXED, __HIP_MEMORY_SCOPE_AGENT)
                    : 0u;
                if (nd_s[m] >= 0 && hv[k2] == SENT_H) ok = false;
            }
            if (nd_s[m0] >= 0 && __builtin_bit_cast(unsigned, cp0) == SENT_C) ok = false;
            if (nd_s[m0 + 8] >= 0 && __builtin_bit_cast(unsigned, cp1) == SENT_C) ok = false;
            if (!__syncthreads_and(ok ? 1 : 0)) {
                // Miss path: cheap 16-lane sentry (idle blocks live here),
                // then per-word revalidation of only still-sentinel words.
                if (tid < 64) {
                    const int m = tid & 15;
                    const bool act = (tid < 16) && (nd_s[m] >= 0);
                    const unsigned* sp = &HbU[(size_t)par_s[m] * 128 + j * 16];
                    bool miss = act && (__hip_atomic_load(sp, __ATOMIC_RELAXED,
                                                          __HIP_MEMORY_SCOPE_AGENT) == SENT_H);
                    while (__any(miss ? 1 : 0))
                        miss = act && (__hip_atomic_load(sp, __ATOMIC_RELAXED,
                                                         __HIP_MEMORY_SCOPE_AGENT) == SENT_H);
                }
                __syncthreads();
                if (nd_s[m0] >= 0)
                    while (__builtin_bit_cast(unsigned, cp0) == SENT_C) {
                        __builtin_amdgcn_s_sleep(1);
                        cp0 = __hip_atomic_load(cpp0, __ATOMIC_RELAXED, __HIP_MEMORY_SCOPE_AGENT);
                    }
                if (nd_s[m0 + 8] >= 0)
                    while (__builtin_bit_cast(unsigned, cp1) == SENT_C) {
                        __builtin_amdgcn_s_sleep(1);
                        cp1 = __hip_atomic_load(cpp1, __ATOMIC_RELAXED, __HIP_MEMORY_SCOPE_AGENT);
                    }
                #pragma unroll
                for (int k2 = 0; k2 < 8; ++k2) {
                    const int e = tid + k2 * 256, m = e >> 7, cu = e & 127;
                    if (nd_s[m] >= 0)
                        while (hv[k2] == SENT_H) {
                            __builtin_amdgcn_s_sleep(1);
                            hv[k2] = __hip_atomic_load(&HbU[(size_t)par_s[m] * 128 + cu],
                                                       __ATOMIC_RELAXED, __HIP_MEMORY_SCOPE_AGENT);
                        }
                }
            }
            // Stage parent H into LDS.
            #pragma unroll
            for (int k2 = 0; k2 < 8; ++k2) {
                const int e = tid + k2 * 256, m = e >> 7, cu = e & 127;
                *(unsigned*)&A_s[m * 264 + cu * 2] = hv[k2];
            }
            __syncthreads();
            // M=16 K=256 MFMA -> R_s
            {
                short8 af[8];
                #pragma unroll
                for (int ks = 0; ks < 8; ++ks)
                    af[ks] = *(const short8*)&A_s[lanelo * 264 + ks * 32 + quad * 8];
                #pragma unroll
                for (int ti = 0; ti < 2; ++ti) {
                    int ntl = w * 2 + ti;
                    float4_ acc = (float4_){0.f, 0.f, 0.f, 0.f};
                    #pragma unroll
                    for (int ks = 0; ks < 8; ++ks) {
                        short8 bf = *(const short8*)&w_s[(ntl * 16 + lanelo) * 264 + ks * 32 + quad * 8];
                        acc = __builtin_amdgcn_mfma_f32_16x16x32_bf16(af[ks], bf, acc, 0, 0, 0);
                    }
                    #pragma unroll
                    for (int r = 0; r < 4; ++r)
                        R_s[(quad * 4 + r) * 132 + ntl * 16 + lanelo] = acc[r];
                }
            }
            __syncthreads();
            // Elementwise LSTM for the block's 32 cols; relaxed stores, then
            // per-tile wg-release fence (s_waitcnt only) for prompt drain.
            {
                #pragma unroll
                for (int pass = 0; pass < 2; ++pass) {
                    int m = m0 + pass * 8;
                    float cp = pass ? cp1 : cp0;
                    float ig = R_s[m * 132 + c0]      + G_s[m * 128 + c0];
                    float fg = R_s[m * 132 + 32 + c0] + G_s[m * 128 + 32 + c0];
                    float gg = R_s[m * 132 + 64 + c0] + G_s[m * 128 + 64 + c0];
                    float og = R_s[m * 132 + 96 + c0] + G_s[m * 128 + 96 + c0];
                    float cn = sigf(fg) * cp + sigf(ig) * tanh_(gg);
                    float hn = sigf(og) * tanh_(cn);
                    int node = nd_s[m];
                    unsigned short hs = f2bf(hn);
                    unsigned pair = ((unsigned)hs) |
                                    (((unsigned)(unsigned short)__shfl_down((int)hs, 1)) << 16);
                    if (node >= 0) {
                        __hip_atomic_store(&C[(size_t)node * DD + col], cn,
                                           __ATOMIC_RELAXED, __HIP_MEMORY_SCOPE_AGENT);
                        if ((c0 & 1) == 0)
                            __hip_atomic_store(&((unsigned*)Hb)[(size_t)node * 128 + (col >> 1)],
                                               pair, __ATOMIC_RELAXED, __HIP_MEMORY_SCOPE_AGENT);
                    }
                }
            }
            __builtin_amdgcn_fence(__ATOMIC_RELEASE, "workgroup");
            __syncthreads();
        }
        lo = hi;
    }
    #undef OFFS
}

__global__ void k_out(const unsigned short* __restrict__ Hb, const float* __restrict__ C,
                      const int* __restrict__ idx, float* __restrict__ out) {
    const int b = blockIdx.x, t = threadIdx.x;
    if (b < NN) {
        int drow = idx[b];
        out[512 + (size_t)drow * DD + t] = bf2f(Hb[(size_t)b * DD + t]);
    } else {
        out[t] = C[t];
        out[DD + t] = bf2f(Hb[t]);
    }
}

extern "C" void kernel_launch(void* const* d_in, const int* in_sizes, int n_in,
                              void* d_out, int out_size, void* d_ws, size_t ws_size,
                              hipStream_t stream) {
    const float* X     = (const float*)d_in[0];
    const float* state = (const float*)d_in[1];
    const float* rootW = (const float*)d_in[2];
    const float* rootb = (const float*)d_in[3];
    const float* Wih   = (const float*)d_in[4];
    const float* Whh   = (const float*)d_in[5];
    const float* bih   = (const float*)d_in[6];
    const float* bhh   = (const float*)d_in[7];
    const int* parents = (const int*)d_in[8];
    const int* idx     = (const int*)d_in[9];

    float* C           = (float*)d_ws;                                   // 32 MiB
    unsigned short* Hb = (unsigned short*)(C + (size_t)NN * DD);         // 16 MiB
    unsigned short* Gp = Hb + (size_t)NN * DD;                           // 64 MiB
    int* ip            = (int*)(Gp + (size_t)NN * GP);
    int* depA = ip;            ip += NN;
    int* jmpA = ip;            ip += NN;
    int* depB = ip;            ip += NN;
    int* jmpB = ip;            ip += NN;
    int* cnt  = ip;            ip += NN + 2;
    int* off  = ip;            ip += NN + 2;
    int* cur  = ip;            ip += NN + 2;
    int* lev  = ip;            ip += NN;
    int* maxd = ip;            ip += 4;
    float* out = (float*)d_out;

    k_init<<<dim3(2048), dim3(256), 0, stream>>>(cnt, cur, maxd, C, (unsigned*)Hb);
    k_root<<<dim3(1), dim3(256), 0, stream>>>(X, state, rootW, rootb, idx, Hb, C);

    k_dep_init<<<dim3(128), dim3(256), 0, stream>>>(parents, depA, jmpA);
    int* dA = depA; int* jA = jmpA; int* dB = depB; int* jB = jmpB;
    for (int it = 0; it < 15; ++it) {
        k_dep_step<<<dim3(128), dim3(256), 0, stream>>>(dA, jA, dB, jB);
        int* tp;
        tp = dA; dA = dB; dB = tp;
        tp = jA; jA = jB; jB = tp;
    }
    k_hist<<<dim3(128), dim3(256), 0, stream>>>(dA, cnt, maxd);
    k_scan<<<dim3(1), dim3(256), 0, stream>>>(cnt, off);
    k_scatter<<<dim3(128), dim3(256), 0, stream>>>(dA, off, cur, lev);

    k_gx<<<dim3(256), dim3(256), 0, stream>>>(X, Wih, bih, bhh, idx, Gp);
    k_tree2<<<dim3(256), dim3(256), 0, stream>>>(Whh, parents, off, lev, maxd, Gp, Hb, C);
    k_out<<<dim3(NN + 1), dim3(256), 0, stream>>>(Hb, C, idx, out);
}